// Round 1
// baseline (2888.643 us; speedup 1.0000x reference)
//
#include <hip/hip_runtime.h>

// GCN 2-layer: out = GCNConv(relu(GCNConv(x, W1, b1)), W2, b2)
// N=100000, F_in=512, H=16, C=40, E=3200000 (+self loops in normalization)

#define TPB 256

// ---------------------------------------------------------------- init
__global__ void k_init(float* __restrict__ deg, float* __restrict__ agg1,
                       float* __restrict__ agg2, int n) {
    int i = blockIdx.x * TPB + threadIdx.x;
    if (i < n) deg[i] = 1.0f;            // self-loop contribution
    if (i < n * 16) agg1[i] = 0.0f;
    if (i < n * 40) agg2[i] = 0.0f;
}

// ---------------------------------------------------------------- degree
__global__ void k_deg(const int* __restrict__ dst, float* __restrict__ deg, int E) {
    int e = blockIdx.x * TPB + threadIdx.x;
    if (e < E) atomicAdd(&deg[dst[e]], 1.0f);
}

__global__ void k_dinv(const float* __restrict__ deg, float* __restrict__ dinv, int n) {
    int i = blockIdx.x * TPB + threadIdx.x;
    if (i < n) dinv[i] = rsqrtf(deg[i]);   // deg >= 1 always (self loop)
}

// ---------------------------------------------------------------- GEMM1: h1[n,16] = x[n,512] @ W1[512,16]
// Block: 256 threads, 256 rows. Thread tile: 4 rows x 4 cols.
// LDS: x chunk [256 rows][32 k] (+pad to 36 for alignment/banks), W chunk [32][16].
#define G1_ROWS 256
#define G1_KC 32
__global__ __launch_bounds__(TPB) void k_gemm1(const float* __restrict__ x,
                                               const float* __restrict__ W,
                                               float* __restrict__ h, int n) {
    __shared__ float xs[G1_ROWS][36];   // stride 36 floats = 144B (16B aligned)
    __shared__ float wl[G1_KC][16];
    const int tid = threadIdx.x;
    const int row0 = blockIdx.x * G1_ROWS;
    const int rg = tid >> 2;            // 0..63
    const int c0 = (tid & 3) * 4;       // 0,4,8,12

    float acc[4][4];
#pragma unroll
    for (int j = 0; j < 4; ++j)
#pragma unroll
        for (int c = 0; c < 4; ++c) acc[j][c] = 0.0f;

    for (int kc = 0; kc < 512; kc += G1_KC) {
        __syncthreads();
        // stage x: 256 rows x 32 k = 2048 float4 -> 8 per thread, coalesced
#pragma unroll
        for (int t = 0; t < 8; ++t) {
            int f4 = tid + TPB * t;          // 0..2047
            int row = f4 >> 3;               // 8 float4 per row
            int kk = (f4 & 7) * 4;
            int grow = row0 + row;
            if (grow >= n) grow = n - 1;     // clamp (results guarded at store)
            float4 v = *reinterpret_cast<const float4*>(&x[(size_t)grow * 512 + kc + kk]);
            *reinterpret_cast<float4*>(&xs[row][kk]) = v;
        }
        // stage W chunk: 32x16 floats = 128 float4
        if (tid < 128) {
            int k = tid >> 2, cc = (tid & 3) * 4;
            *reinterpret_cast<float4*>(&wl[k][cc]) =
                *reinterpret_cast<const float4*>(&W[(size_t)(kc + k) * 16 + cc]);
        }
        __syncthreads();

#pragma unroll
        for (int k4 = 0; k4 < G1_KC; k4 += 4) {
            float w[4][4];
#pragma unroll
            for (int kk = 0; kk < 4; ++kk) {
                float4 wv = *reinterpret_cast<const float4*>(&wl[k4 + kk][c0]);
                w[kk][0] = wv.x; w[kk][1] = wv.y; w[kk][2] = wv.z; w[kk][3] = wv.w;
            }
#pragma unroll
            for (int j = 0; j < 4; ++j) {
                float4 xv = *reinterpret_cast<const float4*>(&xs[rg + 64 * j][k4]);
                float xk[4] = {xv.x, xv.y, xv.z, xv.w};
#pragma unroll
                for (int kk = 0; kk < 4; ++kk)
#pragma unroll
                    for (int c = 0; c < 4; ++c) acc[j][c] += xk[kk] * w[kk][c];
            }
        }
    }

#pragma unroll
    for (int j = 0; j < 4; ++j) {
        int grow = row0 + rg + 64 * j;
        if (grow < n) {
            float4 v = make_float4(acc[j][0], acc[j][1], acc[j][2], acc[j][3]);
            *reinterpret_cast<float4*>(&h[(size_t)grow * 16 + c0]) = v;
        }
    }
}

// ---------------------------------------------------------------- edge scatter layer1 (F=16)
__global__ void k_agg1(const int* __restrict__ src, const int* __restrict__ dst,
                       const float* __restrict__ dinv, const float* __restrict__ h,
                       float* __restrict__ agg, int E) {
    int gid = blockIdx.x * TPB + threadIdx.x;
    int e = gid >> 4;
    if (e >= E) return;
    int f = gid & 15;
    int s = src[e], d = dst[e];
    float nrm = dinv[s] * dinv[d];
    atomicAdd(&agg[(size_t)d * 16 + f], h[(size_t)s * 16 + f] * nrm);
}

// ---------------------------------------------------------------- post1: h2 = relu(agg1 + dinv^2*h1 + b1) (in-place into agg1)
__global__ void k_post1(float* __restrict__ agg, const float* __restrict__ h1,
                        const float* __restrict__ dinv, const float* __restrict__ b, int n) {
    int gid = blockIdx.x * TPB + threadIdx.x;
    if (gid >= n * 16) return;
    int i = gid >> 4, f = gid & 15;
    float di = dinv[i];
    float v = agg[gid] + di * di * h1[gid] + b[f];
    agg[gid] = fmaxf(v, 0.0f);
}

// ---------------------------------------------------------------- GEMM2: h3[n,40] = h2[n,16] @ W2[16,40]
__global__ void k_gemm2(const float* __restrict__ h2, const float* __restrict__ W2,
                        float* __restrict__ h3, int n) {
    __shared__ float wl[16 * 40];
    int tid = threadIdx.x;
    for (int i = tid; i < 640; i += TPB) wl[i] = W2[i];
    __syncthreads();
    int gid = blockIdx.x * TPB + tid;
    if (gid >= n * 40) return;
    int r = gid / 40, c = gid - r * 40;
    const float* hr = &h2[(size_t)r * 16];
    float a = 0.0f;
#pragma unroll
    for (int k = 0; k < 16; ++k) a += hr[k] * wl[k * 40 + c];
    h3[gid] = a;
}

// ---------------------------------------------------------------- edge scatter layer2 (F=40), 8 lanes/edge x 5 feats
__global__ void k_agg2(const int* __restrict__ src, const int* __restrict__ dst,
                       const float* __restrict__ dinv, const float* __restrict__ h,
                       float* __restrict__ agg, int E) {
    int gid = blockIdx.x * TPB + threadIdx.x;
    int e = gid >> 3;
    if (e >= E) return;
    int f0 = (gid & 7) * 5;
    int s = src[e], d = dst[e];
    float nrm = dinv[s] * dinv[d];
    const float* hs = &h[(size_t)s * 40 + f0];
    float* ad = &agg[(size_t)d * 40 + f0];
#pragma unroll
    for (int q = 0; q < 5; ++q) atomicAdd(&ad[q], hs[q] * nrm);
}

// ---------------------------------------------------------------- post2: out = agg2 + dinv^2*h3 + b2
__global__ void k_post2(const float* __restrict__ agg, const float* __restrict__ h3,
                        const float* __restrict__ dinv, const float* __restrict__ b,
                        float* __restrict__ out, int n) {
    int gid = blockIdx.x * TPB + threadIdx.x;
    if (gid >= n * 40) return;
    int i = gid / 40, c = gid - i * 40;
    float di = dinv[i];
    out[gid] = agg[gid] + di * di * h3[gid] + b[c];
}

extern "C" void kernel_launch(void* const* d_in, const int* in_sizes, int n_in,
                              void* d_out, int out_size, void* d_ws, size_t ws_size,
                              hipStream_t stream) {
    const float* x  = (const float*)d_in[0];
    const int*   ei = (const int*)d_in[1];
    const float* W1 = (const float*)d_in[2];
    const float* b1 = (const float*)d_in[3];
    const float* W2 = (const float*)d_in[4];
    const float* b2 = (const float*)d_in[5];
    float* out = (float*)d_out;

    const int n = in_sizes[0] / 512;
    const int E = in_sizes[1] / 2;
    const int* src = ei;
    const int* dst = ei + E;

    float* ws   = (float*)d_ws;
    float* deg  = ws;                      // n
    float* dinv = ws + (size_t)n;          // n
    float* h1   = ws + (size_t)2 * n;      // 16n
    float* agg1 = ws + (size_t)18 * n;     // 16n (becomes h2 after post1)
    float* h3   = ws + (size_t)34 * n;     // 40n
    float* agg2 = ws + (size_t)74 * n;     // 40n  -> total 114n floats = 45.6 MB

    k_init<<<(n * 40 + TPB - 1) / TPB, TPB, 0, stream>>>(deg, agg1, agg2, n);
    k_deg<<<(E + TPB - 1) / TPB, TPB, 0, stream>>>(dst, deg, E);
    k_dinv<<<(n + TPB - 1) / TPB, TPB, 0, stream>>>(deg, dinv, n);
    k_gemm1<<<(n + G1_ROWS - 1) / G1_ROWS, TPB, 0, stream>>>(x, W1, h1, n);
    k_agg1<<<(int)(((size_t)E * 16 + TPB - 1) / TPB), TPB, 0, stream>>>(src, dst, dinv, h1, agg1, E);
    k_post1<<<(n * 16 + TPB - 1) / TPB, TPB, 0, stream>>>(agg1, h1, dinv, b1, n);
    k_gemm2<<<(n * 40 + TPB - 1) / TPB, TPB, 0, stream>>>(agg1, W2, h3, n);
    k_agg2<<<(int)(((size_t)E * 8 + TPB - 1) / TPB), TPB, 0, stream>>>(src, dst, dinv, h3, agg2, E);
    k_post2<<<(n * 40 + TPB - 1) / TPB, TPB, 0, stream>>>(agg2, h3, dinv, b2, out, n);
}

// Round 2
// 584.197 us; speedup vs baseline: 4.9446x; 4.9446x over previous
//
#include <hip/hip_runtime.h>

// GCN 2-layer: out = GCNConv(relu(GCNConv(x, W1, b1)), W2, b2)
// N=100000, F_in=512, H=16, C=40, E=3200000 (+self loops in normalization)
// Layer 2 uses aggregate-then-transform: A_hat(h2 W2) == (A_hat h2) W2,
// so both edge scatters run in 16-dim feature space.

#define TPB 256

// ---------------------------------------------------------------- init
__global__ void k_init(float* __restrict__ deg, float* __restrict__ agg1,
                       float* __restrict__ agg2, int n) {
    int i = blockIdx.x * TPB + threadIdx.x;
    if (i < n) deg[i] = 1.0f;            // self-loop contribution
    if (i < n * 16) { agg1[i] = 0.0f; agg2[i] = 0.0f; }
}

// ---------------------------------------------------------------- degree
__global__ void k_deg(const int* __restrict__ dst, float* __restrict__ deg, int E) {
    int e = blockIdx.x * TPB + threadIdx.x;
    if (e < E) atomicAdd(&deg[dst[e]], 1.0f);
}

__global__ void k_dinv(const float* __restrict__ deg, float* __restrict__ dinv, int n) {
    int i = blockIdx.x * TPB + threadIdx.x;
    if (i < n) dinv[i] = rsqrtf(deg[i]);   // deg >= 1 always (self loop)
}

// ---------------------------------------------------------------- GEMM1: h1[n,16] = x[n,512] @ W1[512,16]
#define G1_ROWS 256
#define G1_KC 32
__global__ __launch_bounds__(TPB) void k_gemm1(const float* __restrict__ x,
                                               const float* __restrict__ W,
                                               float* __restrict__ h, int n) {
    __shared__ float xs[G1_ROWS][36];   // stride 36 floats (16B aligned, bank-skewed)
    __shared__ float wl[G1_KC][16];
    const int tid = threadIdx.x;
    const int row0 = blockIdx.x * G1_ROWS;
    const int rg = tid >> 2;            // 0..63
    const int c0 = (tid & 3) * 4;       // 0,4,8,12

    float acc[4][4];
#pragma unroll
    for (int j = 0; j < 4; ++j)
#pragma unroll
        for (int c = 0; c < 4; ++c) acc[j][c] = 0.0f;

    for (int kc = 0; kc < 512; kc += G1_KC) {
        __syncthreads();
#pragma unroll
        for (int t = 0; t < 8; ++t) {
            int f4 = tid + TPB * t;          // 0..2047
            int row = f4 >> 3;               // 8 float4 per row
            int kk = (f4 & 7) * 4;
            int grow = row0 + row;
            if (grow >= n) grow = n - 1;     // clamp (results guarded at store)
            float4 v = *reinterpret_cast<const float4*>(&x[(size_t)grow * 512 + kc + kk]);
            *reinterpret_cast<float4*>(&xs[row][kk]) = v;
        }
        if (tid < 128) {
            int k = tid >> 2, cc = (tid & 3) * 4;
            *reinterpret_cast<float4*>(&wl[k][cc]) =
                *reinterpret_cast<const float4*>(&W[(size_t)(kc + k) * 16 + cc]);
        }
        __syncthreads();

#pragma unroll
        for (int k4 = 0; k4 < G1_KC; k4 += 4) {
            float w[4][4];
#pragma unroll
            for (int kk = 0; kk < 4; ++kk) {
                float4 wv = *reinterpret_cast<const float4*>(&wl[k4 + kk][c0]);
                w[kk][0] = wv.x; w[kk][1] = wv.y; w[kk][2] = wv.z; w[kk][3] = wv.w;
            }
#pragma unroll
            for (int j = 0; j < 4; ++j) {
                float4 xv = *reinterpret_cast<const float4*>(&xs[rg + 64 * j][k4]);
                float xk[4] = {xv.x, xv.y, xv.z, xv.w};
#pragma unroll
                for (int kk = 0; kk < 4; ++kk)
#pragma unroll
                    for (int c = 0; c < 4; ++c) acc[j][c] += xk[kk] * w[kk][c];
            }
        }
    }

#pragma unroll
    for (int j = 0; j < 4; ++j) {
        int grow = row0 + rg + 64 * j;
        if (grow < n) {
            float4 v = make_float4(acc[j][0], acc[j][1], acc[j][2], acc[j][3]);
            *reinterpret_cast<float4*>(&h[(size_t)grow * 16 + c0]) = v;
        }
    }
}

// ---------------------------------------------------------------- edge scatter (F=16): agg[d] += dinv[s]*dinv[d]*h[s]
// 16 lanes per edge, one float each -> 64B per edge, lane-consecutive atomics.
__global__ void k_agg(const int* __restrict__ src, const int* __restrict__ dst,
                      const float* __restrict__ dinv, const float* __restrict__ h,
                      float* __restrict__ agg, int E) {
    int gid = blockIdx.x * TPB + threadIdx.x;
    int e = gid >> 4;
    if (e >= E) return;
    int f = gid & 15;
    int s = src[e], d = dst[e];
    float nrm = dinv[s] * dinv[d];
    atomicAdd(&agg[(size_t)d * 16 + f], h[(size_t)s * 16 + f] * nrm);
}

// ---------------------------------------------------------------- post1: h2 = relu(agg1 + dinv^2*h1 + b1) (in-place into agg1)
__global__ void k_post1(float* __restrict__ agg, const float* __restrict__ h1,
                        const float* __restrict__ dinv, const float* __restrict__ b, int n) {
    int gid = blockIdx.x * TPB + threadIdx.x;
    if (gid >= n * 16) return;
    int i = gid >> 4, f = gid & 15;
    float di = dinv[i];
    float v = agg[gid] + di * di * h1[gid] + b[f];
    agg[gid] = fmaxf(v, 0.0f);
}

// ---------------------------------------------------------------- fused GEMM2+self-loop+bias:
// out[i,:] = (agg2[i,:] + dinv[i]^2 * h2[i,:]) @ W2 + b2
__global__ void k_gemm2f(const float* __restrict__ agg2, const float* __restrict__ h2,
                         const float* __restrict__ dinv, const float* __restrict__ W2,
                         const float* __restrict__ b2, float* __restrict__ out, int n) {
    __shared__ float wl[16 * 40];
    __shared__ float bl[40];
    int tid = threadIdx.x;
    for (int i = tid; i < 640; i += TPB) wl[i] = W2[i];
    if (tid < 40) bl[tid] = b2[tid];
    __syncthreads();
    int gid = blockIdx.x * TPB + tid;
    if (gid >= n * 40) return;
    int r = gid / 40, c = gid - r * 40;
    float di = dinv[r];
    float d2 = di * di;
    const float* ar = &agg2[(size_t)r * 16];
    const float* hr = &h2[(size_t)r * 16];
    float a = bl[c];
#pragma unroll
    for (int k = 0; k < 16; ++k) a += (ar[k] + d2 * hr[k]) * wl[k * 40 + c];
    out[gid] = a;
}

extern "C" void kernel_launch(void* const* d_in, const int* in_sizes, int n_in,
                              void* d_out, int out_size, void* d_ws, size_t ws_size,
                              hipStream_t stream) {
    const float* x  = (const float*)d_in[0];
    const int*   ei = (const int*)d_in[1];
    const float* W1 = (const float*)d_in[2];
    const float* b1 = (const float*)d_in[3];
    const float* W2 = (const float*)d_in[4];
    const float* b2 = (const float*)d_in[5];
    float* out = (float*)d_out;

    const int n = in_sizes[0] / 512;
    const int E = in_sizes[1] / 2;
    const int* src = ei;
    const int* dst = ei + E;

    float* ws   = (float*)d_ws;
    float* deg  = ws;                      // n
    float* dinv = ws + (size_t)n;          // n
    float* h1   = ws + (size_t)2 * n;      // 16n
    float* agg1 = ws + (size_t)18 * n;     // 16n (becomes h2 after post1)
    float* agg2 = ws + (size_t)34 * n;     // 16n  -> total 50n floats = 20 MB

    k_init<<<(n * 16 + TPB - 1) / TPB, TPB, 0, stream>>>(deg, agg1, agg2, n);
    k_deg<<<(E + TPB - 1) / TPB, TPB, 0, stream>>>(dst, deg, E);
    k_dinv<<<(n + TPB - 1) / TPB, TPB, 0, stream>>>(deg, dinv, n);
    k_gemm1<<<(n + G1_ROWS - 1) / G1_ROWS, TPB, 0, stream>>>(x, W1, h1, n);
    k_agg<<<(int)(((size_t)E * 16 + TPB - 1) / TPB), TPB, 0, stream>>>(src, dst, dinv, h1, agg1, E);
    k_post1<<<(n * 16 + TPB - 1) / TPB, TPB, 0, stream>>>(agg1, h1, dinv, b1, n);
    k_agg<<<(int)(((size_t)E * 16 + TPB - 1) / TPB), TPB, 0, stream>>>(src, dst, dinv, agg1, agg2, E);
    k_gemm2f<<<(n * 40 + TPB - 1) / TPB, TPB, 0, stream>>>(agg2, agg1, dinv, W2, b2, out, n);
}